// Round 5
// baseline (70.698 us; speedup 1.0000x reference)
//
#include <hip/hip_runtime.h>

// 2-layer EfficientKAN — exact per-cell monomial evaluation, single kernel,
// float4 I/O. Final refinement round.
//
// R4 post-mortem: three structurally unrelated kernels (R0/R2/R4) landed at
// 73.6/70.9/69.8 us total => the ~65 us base is harness-fixed (40.3 us
// 268 MB poison fill @83% HBM + ~25 us serial tiny restores/launch overhead),
// NOT kernel time. Kernel is ~5 us vs its ~3.5 us LDS-pipe floor
// (256 LDS bytes/sample = 2.6 us aggregate; VALU ~1 us; HBM 4 MB ~0.6 us).
//
// This version closes the remaining gap:
//  * float4 I/O (16 B/lane, coalescing sweet spot) — R4 used scalar 4 B.
//  * x prefetch issued BEFORE the LDS table build + __syncthreads, hiding
//    ~900 cyc HBM latency under setup.
//  * exact grid: 131072 float4 = 512 blocks x 256 threads, no tail.
//  * per-cell monomial coeff tables (1 ds_read_b128 + 3-FMA Horner per
//    spline eval), stride-9 rows => bank group (cell+o)%8 spread.
//
// Out-of-range: s=(x+2.2)/0.4 clamped to [0,13.9999]; guard cells are exact
// zeros, matching reference zero-outside-support.

__device__ __forceinline__ float silu_fast(float x) {
    return x * __builtin_amdgcn_rcpf(1.0f + __expf(-x));
}

#define STRIDE 9   // float4s per cell row; 9 % 8 == 1 -> bank spread

__global__ __launch_bounds__(256) void kan2_cell4(
    const float* __restrict__ bw1, const float* __restrict__ sw1,
    const float* __restrict__ sc1, const float* __restrict__ bw2,
    const float* __restrict__ sw2, const float* __restrict__ sc2,
    const float4* __restrict__ x4, float4* __restrict__ out4, int n4)
{
    __shared__ __align__(16) float4 c1[14 * STRIDE];  // layer-1 spline coeffs
    __shared__ __align__(16) float4 c2[14 * STRIDE];  // layer-2 spline coeffs
    const int t = threadIdx.x;
    int i = blockIdx.x * 256 + t;

    // ---- prefetch this thread's input before the table build ----
    float4 xv;
    bool valid = (i < n4);
    if (valid) xv = x4[i];

    // ---- build exact per-cell monomial tables (first 112 threads) ----
    if (t < 112) {
        int c = t >> 3, o = t & 7;       // cell 0..13, output/input 0..7
        float w1v[4], w2v[4];
#pragma unroll
        for (int m = 0; m < 4; ++m) {
            int k = c - 3 + m;           // basis index contributing piece m
            bool in = (k >= 0) && (k <= 7);
            w1v[m] = in ? sw1[o * 8 + k] * sc1[o] : 0.0f;
            w2v[m] = in ? sw2[o * 8 + k] * sc2[o] : 0.0f;
        }
        float4 a1, a2;
        a1.x = (w1v[0] + 4.0f * w1v[1] + w1v[2]) * (1.0f / 6.0f);
        a1.y = (w1v[2] - w1v[0]) * 0.5f;
        a1.z = (w1v[0] + w1v[2]) * 0.5f - w1v[1];
        a1.w = (w1v[3] - w1v[0] + 3.0f * (w1v[1] - w1v[2])) * (1.0f / 6.0f);
        a2.x = (w2v[0] + 4.0f * w2v[1] + w2v[2]) * (1.0f / 6.0f);
        a2.y = (w2v[2] - w2v[0]) * 0.5f;
        a2.z = (w2v[0] + w2v[2]) * 0.5f - w2v[1];
        a2.w = (w2v[3] - w2v[0] + 3.0f * (w2v[1] - w2v[2])) * (1.0f / 6.0f);
        c1[c * STRIDE + o] = a1;
        c2[c * STRIDE + o] = a2;
    }

    // uniform base weights -> scalar regs (s_load; overlaps with sync)
    float bw1v[8], bw2v[8];
#pragma unroll
    for (int o = 0; o < 8; ++o) { bw1v[o] = bw1[o]; bw2v[o] = bw2[o]; }

    __syncthreads();

    const int stride = gridDim.x * 256;
    while (true) {
        if (valid) {
            float vin[4] = {xv.x, xv.y, xv.z, xv.w};
            float vout[4];
#pragma unroll
            for (int cpt = 0; cpt < 4; ++cpt) {
                float x = vin[cpt];

                // ---- layer 1: h_o = silu(x)*bw1_o + cubic_{cell}(u) ----
                float s = __fmaf_rn(x, 2.5f, 5.5f);          // (x+2.2)/0.4
                s = fminf(fmaxf(s, 0.0f), 13.999999f);
                float fc = floorf(s);
                int   c  = (int)fc;
                float u  = s - fc;
                float sx = silu_fast(x);

                float h[8];
#pragma unroll
                for (int o = 0; o < 8; ++o) {
                    float4 A = c1[c * STRIDE + o];
                    float p = __fmaf_rn(
                        __fmaf_rn(__fmaf_rn(A.w, u, A.z), u, A.y), u, A.x);
                    h[o] = __fmaf_rn(sx, bw1v[o], p);
                }

                // ---- layer 2: sum_i silu(h_i)*bw2_i + cubic_{cell_i}(u_i) --
                float acc = 0.0f;
#pragma unroll
                for (int o = 0; o < 8; ++o) {
                    float hv = h[o];
                    float s2 = __fmaf_rn(hv, 2.5f, 5.5f);
                    s2 = fminf(fmaxf(s2, 0.0f), 13.999999f);
                    float fc2 = floorf(s2);
                    int   cc  = (int)fc2;
                    float uu  = s2 - fc2;
                    float4 A = c2[cc * STRIDE + o];
                    float p = __fmaf_rn(
                        __fmaf_rn(__fmaf_rn(A.w, uu, A.z), uu, A.y), uu, A.x);
                    acc = __fmaf_rn(silu_fast(hv), bw2v[o], acc + p);
                }
                vout[cpt] = acc;
            }
            float4 r4;
            r4.x = vout[0]; r4.y = vout[1]; r4.z = vout[2]; r4.w = vout[3];
            out4[i] = r4;
        }
        i += stride;                       // robustness only: grid covers n4
        if (i >= n4) break;
        xv = x4[i];
        valid = true;
    }
}

extern "C" void kernel_launch(void* const* d_in, const int* in_sizes, int n_in,
                              void* d_out, int out_size, void* d_ws, size_t ws_size,
                              hipStream_t stream) {
    const float* x   = (const float*)d_in[0];
    const float* bw1 = (const float*)d_in[1];
    const float* sw1 = (const float*)d_in[2];
    const float* sc1 = (const float*)d_in[3];
    const float* bw2 = (const float*)d_in[4];
    const float* sw2 = (const float*)d_in[5];
    const float* sc2 = (const float*)d_in[6];
    float* out = (float*)d_out;
    (void)d_ws; (void)ws_size;

    int n  = in_sizes[0];          // B = 524288, divisible by 4
    int n4 = n / 4;                // 131072 = 512 blocks x 256 threads exactly

    kan2_cell4<<<(n4 + 255) / 256, 256, 0, stream>>>(
        bw1, sw1, sc1, bw2, sw2, sc2,
        (const float4*)x, (float4*)out, n4);
}